// Round 2
// baseline (303.985 us; speedup 1.0000x reference)
//
#include <hip/hip_runtime.h>
#include <math.h>

#define N_NODES 256
#define T_DIM   30000
#define T_PAD   30016   // 938 * 32
#define H_DIM   512
#define L_DIM   256

typedef __attribute__((ext_vector_type(8))) short short8;
typedef __attribute__((ext_vector_type(4))) float floatx4;

// ---------------- P = I + C ----------------
__global__ void k_init_P(float* P, float* dem, float* u) {
    int t = blockIdx.x * blockDim.x + threadIdx.x; // 65536 threads
    P[t] = ((t >> 8) == (t & 255)) ? 1.0f : 0.0f;
    if (t == 0) *dem = 0.0f;
    if (t < 256) u[t] = 0.0f;
}

__global__ void k_count_edges(const int* __restrict__ idx, int E, float* P) {
    int e = blockIdx.x * blockDim.x + threadIdx.x;
    if (e < E) {
        int s = idx[e];
        int d = idx[E + e];
        atomicAdd(&P[d * N_NODES + s], 1.0f);
    }
}

__global__ void k_zero(float* p, int n) {
    int t = blockIdx.x * blockDim.x + threadIdx.x;
    if (t < n) p[t] = 0.0f;
}

// fp32 -> bf16 (RNE)
__device__ __forceinline__ unsigned short f2b(float f) {
    unsigned u = __float_as_uint(f);
    u += 0x7fffu + ((u >> 16) & 1u);
    return (unsigned short)(u >> 16);
}

__device__ __forceinline__ float4 zero4() {
    float4 z; z.x = z.y = z.z = z.w = 0.f; return z;
}

// ---------------- MFMA big GEMM: Y1p[z] = x @ Ws1a (K-slice z) ----------------
// x [256,30000] fp32 rm, W [30000,512] fp32 rm. 1D grid = 8*nz blocks,
// XCD-chunked swizzle so the 8 tile-blocks of one z-slice share one XCD's L2.
// 128x128 tile; BK=32; in-kernel fp32->bf16; B transposed into LDS [col][k].
__global__ __launch_bounds__(256)
void k_gemm_mfma(const float* __restrict__ x, const float* __restrict__ W,
                 float* __restrict__ outp, int kc) {
    __shared__ unsigned short Al[128 * 40]; // [row][k0..31] pad40 (80B, 16B-aligned rows)
    __shared__ unsigned short Bl[128 * 40]; // [col][k0..31] pad40

    const int t = threadIdx.x;
    // bijective XCD swizzle: hw block orig -> logical L; XCD (orig&7) gets a
    // contiguous L-range (q = nz), i.e. whole z-slices (8 tiles each).
    const int orig = blockIdx.x;
    const int q = gridDim.x >> 3;             // = nz (gridDim.x = 8*nz)
    const int L = (orig & 7) * q + (orig >> 3);
    const int tile = L & 7;
    const int colBase = (tile & 3) << 7;
    const int rowBase = (tile >> 2) << 7;
    const int z = L >> 3;
    const int kb0 = z * kc;
    const int kend = min(kb0 + kc, T_PAD);
    const int nchunk = (kend - kb0) >> 5;

    // A staging: 2 threads/row, 16 consecutive k each
    const int s_row  = t >> 1;
    const int s_half = (t & 1) << 4;
    // B staging: k-major (32 k rows), 16 cols per thread
    const int s_k  = t & 31;
    const int s_cq = (t >> 5) << 4;

    // wave / fragment indexing
    const int w    = t >> 6;
    const int wr   = (w >> 1) << 6;   // wave row offset 0/64
    const int wc   = (w & 1) << 6;    // wave col offset 0/64
    const int lane = t & 63;
    const int lm   = lane & 15;
    const int lq   = (lane >> 4) << 3; // k offset 0,8,16,24

    floatx4 acc[4][4];
    #pragma unroll
    for (int i = 0; i < 4; ++i)
        #pragma unroll
        for (int j = 0; j < 4; ++j)
            acc[i][j] = (floatx4){0.f, 0.f, 0.f, 0.f};

    float4 pa[4], pb[4];
    {   // prefetch chunk 0
        const int kg = kb0;
        const float* ap = x + (size_t)(rowBase + s_row) * T_DIM + kg + s_half;
        #pragma unroll
        for (int i = 0; i < 4; ++i)
            pa[i] = (kg + s_half + i * 4 + 4 <= T_DIM) ? *(const float4*)(ap + i * 4)
                                                       : zero4();
        const float* bp = W + (size_t)(kg + s_k) * H_DIM + colBase + s_cq;
        #pragma unroll
        for (int i = 0; i < 4; ++i)
            pb[i] = (kg + s_k < T_DIM) ? *(const float4*)(bp + i * 4) : zero4();
    }

    #pragma unroll 1
    for (int c = 0; c < nchunk; ++c) {
        __syncthreads();
        // A: convert 16 floats -> 4x ds_write_b64
        #pragma unroll
        for (int i = 0; i < 4; ++i) {
            ushort4 uv;
            uv.x = f2b(pa[i].x); uv.y = f2b(pa[i].y);
            uv.z = f2b(pa[i].z); uv.w = f2b(pa[i].w);
            *(ushort4*)&Al[s_row * 40 + s_half + i * 4] = uv;
        }
        // B: transpose-convert, 16 scalar u16 writes (<=4-way conflicts)
        #pragma unroll
        for (int i = 0; i < 4; ++i) {
            const int cb = s_cq + i * 4;
            Bl[(cb + 0) * 40 + s_k] = f2b(pb[i].x);
            Bl[(cb + 1) * 40 + s_k] = f2b(pb[i].y);
            Bl[(cb + 2) * 40 + s_k] = f2b(pb[i].z);
            Bl[(cb + 3) * 40 + s_k] = f2b(pb[i].w);
        }
        __syncthreads();

        if (c + 1 < nchunk) { // register prefetch next chunk
            const int kg = kb0 + (c + 1) * 32;
            const float* ap = x + (size_t)(rowBase + s_row) * T_DIM + kg + s_half;
            #pragma unroll
            for (int i = 0; i < 4; ++i)
                pa[i] = (kg + s_half + i * 4 + 4 <= T_DIM)
                            ? *(const float4*)(ap + i * 4) : zero4();
            const float* bp = W + (size_t)(kg + s_k) * H_DIM + colBase + s_cq;
            #pragma unroll
            for (int i = 0; i < 4; ++i)
                pb[i] = (kg + s_k < T_DIM) ? *(const float4*)(bp + i * 4) : zero4();
        }

        short8 af[4], bf[4];
        #pragma unroll
        for (int i = 0; i < 4; ++i)
            af[i] = *(const short8*)&Al[(wr + i * 16 + lm) * 40 + lq];
        #pragma unroll
        for (int j = 0; j < 4; ++j)
            bf[j] = *(const short8*)&Bl[(wc + j * 16 + lm) * 40 + lq];
        #pragma unroll
        for (int i = 0; i < 4; ++i)
            #pragma unroll
            for (int j = 0; j < 4; ++j)
                acc[i][j] = __builtin_amdgcn_mfma_f32_16x16x32_bf16(
                    af[i], bf[j], acc[i][j], 0, 0, 0);
    }

    // epilogue: D rows = quad*4+reg, col = lane&15 (m89-verified layout)
    float* op = outp + (size_t)z * (N_NODES * H_DIM);
    const int rq = (lane >> 4) << 2;
    #pragma unroll
    for (int i = 0; i < 4; ++i) {
        #pragma unroll
        for (int j = 0; j < 4; ++j) {
            const int r  = rowBase + wr + i * 16 + rq;
            const int cc = colBase + wc + j * 16 + lm;
            op[(size_t)(r + 0) * H_DIM + cc] = acc[i][j][0];
            op[(size_t)(r + 1) * H_DIM + cc] = acc[i][j][1];
            op[(size_t)(r + 2) * H_DIM + cc] = acc[i][j][2];
            op[(size_t)(r + 3) * H_DIM + cc] = acc[i][j][3];
        }
    }
}

// fallback fp32 GEMM (atomic) if workspace too small for partials
__global__ __launch_bounds__(256)
void k_gemm_big_atomic(const float* __restrict__ x, const float* __restrict__ W,
                       float* __restrict__ outp, int kc) {
    __shared__ float xs[16 * 140];
    __shared__ float ws[16 * 132];
    const int t  = threadIdx.x;
    const int colBase = blockIdx.x * 128;
    const int rowBase = blockIdx.y * 128;
    const int kb0  = blockIdx.z * kc;
    const int kend = min(kb0 + kc, T_DIM);
    const int nchunk = (kend > kb0) ? ((kend - kb0) >> 4) : 0;
    const int lr  = t >> 2, lkq = (t & 3) * 4;
    const int wkk = t >> 5, wcq = (t & 31) * 4;
    const int tx  = t & 15, ty = t >> 4;
    float acc[8][8];
    #pragma unroll
    for (int i = 0; i < 8; ++i)
        #pragma unroll
        for (int j = 0; j < 8; ++j) acc[i][j] = 0.0f;
    #pragma unroll 1
    for (int c = 0; c < nchunk; ++c) {
        int kb = kb0 + c * 16;
        __syncthreads();
        const float* xp = x + (size_t)(rowBase + lr) * T_DIM + kb + lkq;
        float4 xa = *(const float4*)xp;
        float4 xb = *(const float4*)(xp + (size_t)64 * T_DIM);
        const float* wp = W + (size_t)(kb + wkk) * H_DIM + colBase + wcq;
        float4 wa = *(const float4*)wp;
        float4 wb = *(const float4*)(wp + 8 * H_DIM);
        xs[(lkq + 0) * 140 + lr] = xa.x; xs[(lkq + 1) * 140 + lr] = xa.y;
        xs[(lkq + 2) * 140 + lr] = xa.z; xs[(lkq + 3) * 140 + lr] = xa.w;
        xs[(lkq + 0) * 140 + lr + 64] = xb.x; xs[(lkq + 1) * 140 + lr + 64] = xb.y;
        xs[(lkq + 2) * 140 + lr + 64] = xb.z; xs[(lkq + 3) * 140 + lr + 64] = xb.w;
        *(float4*)&ws[wkk * 132 + wcq]       = wa;
        *(float4*)&ws[(wkk + 8) * 132 + wcq] = wb;
        __syncthreads();
        #pragma unroll
        for (int kk = 0; kk < 16; ++kk) {
            float a[8], b[8];
            *(float4*)&a[0] = *(const float4*)&xs[kk * 140 + ty * 8];
            *(float4*)&a[4] = *(const float4*)&xs[kk * 140 + ty * 8 + 4];
            *(float4*)&b[0] = *(const float4*)&ws[kk * 132 + tx * 8];
            *(float4*)&b[4] = *(const float4*)&ws[kk * 132 + tx * 8 + 4];
            #pragma unroll
            for (int i = 0; i < 8; ++i)
                #pragma unroll
                for (int j = 0; j < 8; ++j)
                    acc[i][j] = fmaf(a[i], b[j], acc[i][j]);
        }
    }
    if (nchunk == 0) return;
    #pragma unroll
    for (int i = 0; i < 8; ++i) {
        int r = rowBase + ty * 8 + i;
        #pragma unroll
        for (int j = 0; j < 8; ++j)
            atomicAdd(&outp[r * H_DIM + colBase + tx * 8 + j], acc[i][j]);
    }
}

// reduce split-K partials -> Y1 (65536 float2 threads, 256 blocks = 1/CU)
__global__ void k_reduce(const float2* __restrict__ Y1p, float2* __restrict__ Y1,
                         int nz) {
    int i = blockIdx.x * blockDim.x + threadIdx.x; // 65536
    float2 s = Y1p[i];
    for (int z = 1; z < nz; ++z) {
        float2 v = Y1p[(size_t)z * 65536 + i];
        s.x += v.x; s.y += v.y;
    }
    Y1[i] = s;
}

// ---------------- stage GEMM: 16x32 tiles, 2x2 outputs/thread ----------------
// out[256 x N] = act(A[256 x K] @ B[K x N] + bias)
// 128 threads/block; grid = 16 row-tiles x (N/32) col-tiles.
// N=512 -> 256 blocks (1/CU). 2x2 register blocking: 0.5 ds_read per FMA
// (b64 pair loads) vs 2 scalar reads in the old 1-output/thread version.
// MODE 0: store; MODE 1: + dementia dot; MODE 2: u-fuse, no store.
template<int K, int N, int MODE>
__global__ __launch_bounds__(128)
void k_stage(const float* __restrict__ A, const float* __restrict__ B,
             const float* __restrict__ bias, float* __restrict__ out, int act,
             const float* __restrict__ Wd, float* __restrict__ dem,
             const float* __restrict__ uW, float* __restrict__ u) {
    __shared__ float As[64 * 18];   // [k][row0..15] pad18 (even -> b64-aligned)
    __shared__ float Bs[64 * 36];   // [k][col0..31] pad36 (16B-aligned float4)
    __shared__ float red[2];
    const int nct = N >> 5;
    const int b = blockIdx.x;
    const int r0 = (b / nct) << 4;
    const int c0 = (b % nct) << 5;
    const int t  = threadIdx.x;
    const int tr = t >> 4;           // thread-row 0..7  (2 rows each)
    const int tc = t & 15;           // thread-col 0..15 (2 cols each)
    const int sar = t >> 3;          // A stage: row 0..15
    const int sak = (t & 7) << 2;    // A stage: k-quad 0..28
    const int sbk = t >> 3;          // B stage: k 0..15 (+16p)
    const int sbc = (t & 7) << 2;    // B stage: col-quad 0..28

    float a00 = 0.f, a01 = 0.f, a10 = 0.f, a11 = 0.f;
    #pragma unroll 1
    for (int kb = 0; kb < K; kb += 64) {
        __syncthreads();
        #pragma unroll
        for (int p = 0; p < 2; ++p) {   // A: 16 rows x 64 k, transpose to [k][row]
            float4 v = *(const float4*)&A[(size_t)(r0 + sar) * K + kb + sak + 32 * p];
            As[(sak + 32 * p + 0) * 18 + sar] = v.x;
            As[(sak + 32 * p + 1) * 18 + sar] = v.y;
            As[(sak + 32 * p + 2) * 18 + sar] = v.z;
            As[(sak + 32 * p + 3) * 18 + sar] = v.w;
        }
        #pragma unroll
        for (int p = 0; p < 4; ++p)     // B: 64 k x 32 cols, float4 copy
            *(float4*)&Bs[(sbk + 16 * p) * 36 + sbc] =
                *(const float4*)&B[(size_t)(kb + sbk + 16 * p) * N + c0 + sbc];
        __syncthreads();
        #pragma unroll
        for (int kk = 0; kk < 64; ++kk) {
            float2 av = *(const float2*)&As[kk * 18 + 2 * tr]; // broadcast x16
            float2 bv = *(const float2*)&Bs[kk * 36 + 2 * tc]; // conflict-free
            a00 = fmaf(av.x, bv.x, a00);
            a01 = fmaf(av.x, bv.y, a01);
            a10 = fmaf(av.y, bv.x, a10);
            a11 = fmaf(av.y, bv.y, a11);
        }
    }
    const int rr = r0 + 2 * tr;
    const int cc = c0 + 2 * tc;
    const float b0 = bias ? bias[cc]     : 0.f;
    const float b1 = bias ? bias[cc + 1] : 0.f;
    float v00 = a00 + b0, v01 = a01 + b1;
    float v10 = a10 + b0, v11 = a11 + b1;
    if (act) {
        v00 = fmaxf(v00, 0.f); v01 = fmaxf(v01, 0.f);
        v10 = fmaxf(v10, 0.f); v11 = fmaxf(v11, 0.f);
    }

    if (MODE == 2) {
        float s0 = v00 * uW[cc] + v01 * uW[cc + 1];
        float s1 = v10 * uW[cc] + v11 * uW[cc + 1];
        #pragma unroll
        for (int off = 8; off; off >>= 1) {
            s0 += __shfl_down(s0, off, 16);
            s1 += __shfl_down(s1, off, 16);
        }
        if (tc == 0) { atomicAdd(&u[rr], s0); atomicAdd(&u[rr + 1], s1); }
        return;
    }
    float2 o0; o0.x = v00; o0.y = v01;
    float2 o1; o1.x = v10; o1.y = v11;
    *(float2*)&out[(size_t)rr * N + cc]       = o0;
    *(float2*)&out[(size_t)(rr + 1) * N + cc] = o1;
    if (MODE == 1) {
        float p = v00 * Wd[rr * 256 + cc] + v01 * Wd[rr * 256 + cc + 1]
                + v10 * Wd[(rr + 1) * 256 + cc] + v11 * Wd[(rr + 1) * 256 + cc + 1];
        #pragma unroll
        for (int off = 32; off; off >>= 1) p += __shfl_down(p, off, 64);
        if (t == 0)  red[0] = p;
        if (t == 64) red[1] = p;
        __syncthreads();
        if (t == 0) atomicAdd(dem, red[0] + red[1]);
    }
}

__device__ __forceinline__ float sigmoidf(float x) {
    return 1.0f / (1.0f + expf(-x));
}

// final: v = P@u per row -> region scores; block 0 emits dementia pred
__global__ __launch_bounds__(256)
void k_final(const float* __restrict__ P, const float* __restrict__ u,
             const float* __restrict__ dem,
             const float* __restrict__ bc2a, const float* __restrict__ Wc2b,
             const float* __restrict__ bc2b, const float* __restrict__ bd,
             float* __restrict__ out) {
    __shared__ float red[4];
    const int b = blockIdx.x, t = threadIdx.x;
    float pv = P[b * 256 + t] * u[t];
    #pragma unroll
    for (int off = 32; off; off >>= 1) pv += __shfl_down(pv, off, 64);
    if ((t & 63) == 0) red[t >> 6] = pv;
    __syncthreads();
    if (t == 0) {
        float v = red[0] + red[1] + red[2] + red[3];
        float h2 = fmaxf(v + bc2a[0], 0.f);
        out[1 + b] = sigmoidf(h2 * Wc2b[0] + bc2b[0]);
        if (b == 0) out[0] = sigmoidf(*dem + bd[0]);
    }
}

extern "C" void kernel_launch(void* const* d_in, const int* in_sizes, int n_in,
                              void* d_out, int out_size, void* d_ws, size_t ws_size,
                              hipStream_t stream) {
    const float* x    = (const float*)d_in[0];
    const int*   idx  = (const int*)d_in[1];
    const float* Ws1a = (const float*)d_in[3];
    const float* bs1a = (const float*)d_in[4];
    const float* Ws1b = (const float*)d_in[5];
    const float* bs1b = (const float*)d_in[6];
    const float* Ws2a = (const float*)d_in[7];
    const float* bs2a = (const float*)d_in[8];
    const float* Ws2b = (const float*)d_in[9];
    const float* bs2b = (const float*)d_in[10];
    const float* Wc1a = (const float*)d_in[11];
    const float* bc1a = (const float*)d_in[12];
    const float* Wc1b = (const float*)d_in[13];
    const float* bc1b = (const float*)d_in[14];
    const float* Wc2a = (const float*)d_in[15];
    const float* bc2a = (const float*)d_in[16];
    const float* Wc2b = (const float*)d_in[17];
    const float* bc2b = (const float*)d_in[18];
    const float* Wd   = (const float*)d_in[19];
    const float* bd   = (const float*)d_in[20];
    float* out = (float*)d_out;
    const int E = in_sizes[1] / 2;

    float* w    = (float*)d_ws;
    float* P    = w;                  // 65536
    float* Y1   = P + 65536;          // 131072
    float* bufA = Y1 + 131072;        // 131072
    float* bufB = bufA + 131072;      // 131072
    float* feat = bufB + 131072;      // 65536
    float* u    = feat + 65536;       // 256
    float* dem  = u + 256;            // 64 (dem + pad)
    float* Y1p  = dem + 64;

    // split-K slicing for the MFMA GEMM: 938 chunks of BK=32 (T_PAD=30016)
    const long long fixed = (long long)(Y1p - w);
    const long long avail = (long long)(ws_size / 4) - fixed;
    int maxsplit = (avail > 0) ? (int)(avail / 131072) : 0;
    int nz = 0, kc = 0;
    const int CH32 = 938;
    if (maxsplit >= 2) {
        int splits = maxsplit < 105 ? maxsplit : 105;   // cps=9 -> 840 blocks, 3.3/CU
        int cps = (CH32 + splits - 1) / splits;
        nz = (CH32 + cps - 1) / cps;
        kc = cps * 32;
    }

    // P = I + C; zero dem, u
    k_init_P<<<256, 256, 0, stream>>>(P, dem, u);
    k_count_edges<<<(E + 255) / 256, 256, 0, stream>>>(idx, E, P);

    // Y1 = x @ Ws1a   (P@(x@W) == (P@x)@W)   — bf16 MFMA, split-K, XCD swizzle
    if (nz > 0) {
        k_gemm_mfma<<<8 * nz, 256, 0, stream>>>(x, Ws1a, Y1p, kc);
        k_reduce<<<256, 256, 0, stream>>>((const float2*)Y1p, (float2*)Y1, nz);
    } else {
        k_zero<<<512, 256, 0, stream>>>(Y1, N_NODES * H_DIM);
        k_gemm_big_atomic<<<dim3(4, 2, 63), 256, 0, stream>>>(x, Ws1a, Y1, 480);
    }

    // stage chain (stream order is the barrier); 16x32 tiles, 2x2/thread
    k_stage<256, 512, 0><<<256, 128, 0, stream>>>(P,    Y1,   bs1a, bufA, 1, 0, 0, 0, 0);
    k_stage<512, 512, 0><<<256, 128, 0, stream>>>(bufA, Ws1b, bs1b, bufB, 1, 0, 0, 0, 0);
    k_stage<256, 512, 0><<<256, 128, 0, stream>>>(P,    bufB, 0,    bufA, 0, 0, 0, 0, 0);
    k_stage<512, 256, 0><<<128, 128, 0, stream>>>(bufA, Ws2a, bs2a, bufB, 1, 0, 0, 0, 0);
    k_stage<256, 256, 1><<<128, 128, 0, stream>>>(bufB, Ws2b, bs2b, feat, 0, Wd, dem, 0, 0);
    k_stage<256, 256, 0><<<128, 128, 0, stream>>>(P,    feat, 0,    bufA, 0, 0, 0, 0, 0);
    k_stage<256, 512, 0><<<256, 128, 0, stream>>>(bufA, Wc1a, bc1a, bufB, 1, 0, 0, 0, 0);
    k_stage<512, 512, 2><<<256, 128, 0, stream>>>(bufB, Wc1b, bc1b, 0,    1, 0, 0, Wc2a, u);
    k_final<<<256, 256, 0, stream>>>(P, u, dem, bc2a, Wc2b, bc2b, bd, out);
}

// Round 3
// 267.719 us; speedup vs baseline: 1.1355x; 1.1355x over previous
//
#include <hip/hip_runtime.h>
#include <math.h>

#define N_NODES 256
#define T_DIM   30000
#define T_PAD   30016   // 938 * 32
#define H_DIM   512
#define L_DIM   256

typedef __attribute__((ext_vector_type(8))) short short8;
typedef __attribute__((ext_vector_type(4))) float floatx4;

// ---------------- P = I + C ----------------
__global__ void k_init_P(float* P, float* dem, float* u) {
    int t = blockIdx.x * blockDim.x + threadIdx.x; // 65536 threads
    P[t] = ((t >> 8) == (t & 255)) ? 1.0f : 0.0f;
    if (t == 0) *dem = 0.0f;
    if (t < 256) u[t] = 0.0f;
}

__global__ void k_count_edges(const int* __restrict__ idx, int E, float* P) {
    int e = blockIdx.x * blockDim.x + threadIdx.x;
    if (e < E) {
        int s = idx[e];
        int d = idx[E + e];
        atomicAdd(&P[d * N_NODES + s], 1.0f);
    }
}

__global__ void k_zero(float* p, int n) {
    int t = blockIdx.x * blockDim.x + threadIdx.x;
    if (t < n) p[t] = 0.0f;
}

// fp32 -> bf16 (RNE)
__device__ __forceinline__ unsigned short f2b(float f) {
    unsigned u = __float_as_uint(f);
    u += 0x7fffu + ((u >> 16) & 1u);
    return (unsigned short)(u >> 16);
}

__device__ __forceinline__ float4 zero4() {
    float4 z; z.x = z.y = z.z = z.w = 0.f; return z;
}

// ---------------- MFMA big GEMM: Y1p[z] = x @ Ws1a (K-slice z) ----------------
// x [256,30000] fp32 rm, W [30000,512] fp32 rm. 1D grid = 8*nz blocks,
// XCD-chunked swizzle so the 8 tile-blocks of one z-slice share one XCD's L2.
// 128x128 tile; BK=32; in-kernel fp32->bf16; B transposed into LDS [col][k].
__global__ __launch_bounds__(256)
void k_gemm_mfma(const float* __restrict__ x, const float* __restrict__ W,
                 float* __restrict__ outp, int kc) {
    __shared__ unsigned short Al[128 * 40]; // [row][k0..31] pad40 (80B, 16B-aligned rows)
    __shared__ unsigned short Bl[128 * 40]; // [col][k0..31] pad40

    const int t = threadIdx.x;
    // bijective XCD swizzle: hw block orig -> logical L; XCD (orig&7) gets a
    // contiguous L-range (q = nz), i.e. whole z-slices (8 tiles each).
    const int orig = blockIdx.x;
    const int q = gridDim.x >> 3;             // = nz (gridDim.x = 8*nz)
    const int L = (orig & 7) * q + (orig >> 3);
    const int tile = L & 7;
    const int colBase = (tile & 3) << 7;
    const int rowBase = (tile >> 2) << 7;
    const int z = L >> 3;
    const int kb0 = z * kc;
    const int kend = min(kb0 + kc, T_PAD);
    const int nchunk = (kend - kb0) >> 5;

    // A staging: 2 threads/row, 16 consecutive k each
    const int s_row  = t >> 1;
    const int s_half = (t & 1) << 4;
    // B staging: k-major (32 k rows), 16 cols per thread
    const int s_k  = t & 31;
    const int s_cq = (t >> 5) << 4;

    // wave / fragment indexing
    const int w    = t >> 6;
    const int wr   = (w >> 1) << 6;   // wave row offset 0/64
    const int wc   = (w & 1) << 6;    // wave col offset 0/64
    const int lane = t & 63;
    const int lm   = lane & 15;
    const int lq   = (lane >> 4) << 3; // k offset 0,8,16,24

    floatx4 acc[4][4];
    #pragma unroll
    for (int i = 0; i < 4; ++i)
        #pragma unroll
        for (int j = 0; j < 4; ++j)
            acc[i][j] = (floatx4){0.f, 0.f, 0.f, 0.f};

    float4 pa[4], pb[4];
    {   // prefetch chunk 0
        const int kg = kb0;
        const float* ap = x + (size_t)(rowBase + s_row) * T_DIM + kg + s_half;
        #pragma unroll
        for (int i = 0; i < 4; ++i)
            pa[i] = (kg + s_half + i * 4 + 4 <= T_DIM) ? *(const float4*)(ap + i * 4)
                                                       : zero4();
        const float* bp = W + (size_t)(kg + s_k) * H_DIM + colBase + s_cq;
        #pragma unroll
        for (int i = 0; i < 4; ++i)
            pb[i] = (kg + s_k < T_DIM) ? *(const float4*)(bp + i * 4) : zero4();
    }

    #pragma unroll 1
    for (int c = 0; c < nchunk; ++c) {
        __syncthreads();
        // A: convert 16 floats -> 4x ds_write_b64
        #pragma unroll
        for (int i = 0; i < 4; ++i) {
            ushort4 uv;
            uv.x = f2b(pa[i].x); uv.y = f2b(pa[i].y);
            uv.z = f2b(pa[i].z); uv.w = f2b(pa[i].w);
            *(ushort4*)&Al[s_row * 40 + s_half + i * 4] = uv;
        }
        // B: transpose-convert, 16 scalar u16 writes (<=4-way conflicts)
        #pragma unroll
        for (int i = 0; i < 4; ++i) {
            const int cb = s_cq + i * 4;
            Bl[(cb + 0) * 40 + s_k] = f2b(pb[i].x);
            Bl[(cb + 1) * 40 + s_k] = f2b(pb[i].y);
            Bl[(cb + 2) * 40 + s_k] = f2b(pb[i].z);
            Bl[(cb + 3) * 40 + s_k] = f2b(pb[i].w);
        }
        __syncthreads();

        if (c + 1 < nchunk) { // register prefetch next chunk
            const int kg = kb0 + (c + 1) * 32;
            const float* ap = x + (size_t)(rowBase + s_row) * T_DIM + kg + s_half;
            #pragma unroll
            for (int i = 0; i < 4; ++i)
                pa[i] = (kg + s_half + i * 4 + 4 <= T_DIM)
                            ? *(const float4*)(ap + i * 4) : zero4();
            const float* bp = W + (size_t)(kg + s_k) * H_DIM + colBase + s_cq;
            #pragma unroll
            for (int i = 0; i < 4; ++i)
                pb[i] = (kg + s_k < T_DIM) ? *(const float4*)(bp + i * 4) : zero4();
        }

        short8 af[4], bf[4];
        #pragma unroll
        for (int i = 0; i < 4; ++i)
            af[i] = *(const short8*)&Al[(wr + i * 16 + lm) * 40 + lq];
        #pragma unroll
        for (int j = 0; j < 4; ++j)
            bf[j] = *(const short8*)&Bl[(wc + j * 16 + lm) * 40 + lq];
        #pragma unroll
        for (int i = 0; i < 4; ++i)
            #pragma unroll
            for (int j = 0; j < 4; ++j)
                acc[i][j] = __builtin_amdgcn_mfma_f32_16x16x32_bf16(
                    af[i], bf[j], acc[i][j], 0, 0, 0);
    }

    // epilogue: D rows = quad*4+reg, col = lane&15 (m89-verified layout)
    float* op = outp + (size_t)z * (N_NODES * H_DIM);
    const int rq = (lane >> 4) << 2;
    #pragma unroll
    for (int i = 0; i < 4; ++i) {
        #pragma unroll
        for (int j = 0; j < 4; ++j) {
            const int r  = rowBase + wr + i * 16 + rq;
            const int cc = colBase + wc + j * 16 + lm;
            op[(size_t)(r + 0) * H_DIM + cc] = acc[i][j][0];
            op[(size_t)(r + 1) * H_DIM + cc] = acc[i][j][1];
            op[(size_t)(r + 2) * H_DIM + cc] = acc[i][j][2];
            op[(size_t)(r + 3) * H_DIM + cc] = acc[i][j][3];
        }
    }
}

// fallback fp32 GEMM (atomic) if workspace too small for partials
__global__ __launch_bounds__(256)
void k_gemm_big_atomic(const float* __restrict__ x, const float* __restrict__ W,
                       float* __restrict__ outp, int kc) {
    __shared__ float xs[16 * 140];
    __shared__ float ws[16 * 132];
    const int t  = threadIdx.x;
    const int colBase = blockIdx.x * 128;
    const int rowBase = blockIdx.y * 128;
    const int kb0  = blockIdx.z * kc;
    const int kend = min(kb0 + kc, T_DIM);
    const int nchunk = (kend > kb0) ? ((kend - kb0) >> 4) : 0;
    const int lr  = t >> 2, lkq = (t & 3) * 4;
    const int wkk = t >> 5, wcq = (t & 31) * 4;
    const int tx  = t & 15, ty = t >> 4;
    float acc[8][8];
    #pragma unroll
    for (int i = 0; i < 8; ++i)
        #pragma unroll
        for (int j = 0; j < 8; ++j) acc[i][j] = 0.0f;
    #pragma unroll 1
    for (int c = 0; c < nchunk; ++c) {
        int kb = kb0 + c * 16;
        __syncthreads();
        const float* xp = x + (size_t)(rowBase + lr) * T_DIM + kb + lkq;
        float4 xa = *(const float4*)xp;
        float4 xb = *(const float4*)(xp + (size_t)64 * T_DIM);
        const float* wp = W + (size_t)(kb + wkk) * H_DIM + colBase + wcq;
        float4 wa = *(const float4*)wp;
        float4 wb = *(const float4*)(wp + 8 * H_DIM);
        xs[(lkq + 0) * 140 + lr] = xa.x; xs[(lkq + 1) * 140 + lr] = xa.y;
        xs[(lkq + 2) * 140 + lr] = xa.z; xs[(lkq + 3) * 140 + lr] = xa.w;
        xs[(lkq + 0) * 140 + lr + 64] = xb.x; xs[(lkq + 1) * 140 + lr + 64] = xb.y;
        xs[(lkq + 2) * 140 + lr + 64] = xb.z; xs[(lkq + 3) * 140 + lr + 64] = xb.w;
        *(float4*)&ws[wkk * 132 + wcq]       = wa;
        *(float4*)&ws[(wkk + 8) * 132 + wcq] = wb;
        __syncthreads();
        #pragma unroll
        for (int kk = 0; kk < 16; ++kk) {
            float a[8], b[8];
            *(float4*)&a[0] = *(const float4*)&xs[kk * 140 + ty * 8];
            *(float4*)&a[4] = *(const float4*)&xs[kk * 140 + ty * 8 + 4];
            *(float4*)&b[0] = *(const float4*)&ws[kk * 132 + tx * 8];
            *(float4*)&b[4] = *(const float4*)&ws[kk * 132 + tx * 8 + 4];
            #pragma unroll
            for (int i = 0; i < 8; ++i)
                #pragma unroll
                for (int j = 0; j < 8; ++j)
                    acc[i][j] = fmaf(a[i], b[j], acc[i][j]);
        }
    }
    if (nchunk == 0) return;
    #pragma unroll
    for (int i = 0; i < 8; ++i) {
        int r = rowBase + ty * 8 + i;
        #pragma unroll
        for (int j = 0; j < 8; ++j)
            atomicAdd(&outp[r * H_DIM + colBase + tx * 8 + j], acc[i][j]);
    }
}

// reduce split-K partials -> Y1 (65536 float2 threads, 256 blocks = 1/CU)
__global__ void k_reduce(const float2* __restrict__ Y1p, float2* __restrict__ Y1,
                         int nz) {
    int i = blockIdx.x * blockDim.x + threadIdx.x; // 65536
    float2 s = Y1p[i];
    for (int z = 1; z < nz; ++z) {
        float2 v = Y1p[(size_t)z * 65536 + i];
        s.x += v.x; s.y += v.y;
    }
    Y1[i] = s;
}

// ---------------- MFMA stage GEMM: one 16x16 tile per wave, no LDS ----------------
// out[256 x N] = act(A[256 x K] @ B[K x N] + bias); A,B,out fp32 in memory
// (L2-resident), converted fp32->bf16 in-register for mfma_f32_16x16x32_bf16.
// A-frag: row = lane&15, k = (lane>>4)*8 + 0..7 (2x float4 loads).
// B-frag: col = lane&15, same k slice (8 strided b32 loads, 64B-coalesced
// per 16-lane group). C/D: col = lane&15, row = (lane>>4)*4 + reg (m89).
// Grid: N/4 blocks x 256 thr (4 waves); wave wv owns tile (wv/nct, wv%nct).
// MODE 0: store; MODE 1: store + dementia dot; MODE 2: u-fuse only, no store.
template<int K, int N, int MODE>
__global__ __launch_bounds__(256)
void k_mstage(const float* __restrict__ A, const float* __restrict__ B,
              const float* __restrict__ bias, float* __restrict__ out, int act,
              const float* __restrict__ Wd, float* __restrict__ dem,
              const float* __restrict__ uW, float* __restrict__ u) {
    const int t = threadIdx.x;
    const int wv = (blockIdx.x << 2) | (t >> 6);
    const int nct = N >> 4;
    const int r0 = (wv / nct) << 4;
    const int c0 = (wv % nct) << 4;
    const int lane = t & 63;
    const int lm   = lane & 15;
    const int lq   = (lane >> 4) << 3;   // k slice offset 0,8,16,24

    floatx4 accE = {0.f, 0.f, 0.f, 0.f};
    floatx4 accO = {0.f, 0.f, 0.f, 0.f};
    const float* ap = A + (size_t)(r0 + lm) * K + lq;
    const float* bp = B + (size_t)lq * N + c0 + lm;

    #pragma unroll 2
    for (int kb = 0; kb < K; kb += 64) {
        // ---- k-step kb (even accumulator) ----
        {
            float4 a0 = *(const float4*)(ap + kb);
            float4 a1 = *(const float4*)(ap + kb + 4);
            float b0 = bp[(size_t)(kb + 0) * N], b1 = bp[(size_t)(kb + 1) * N];
            float b2 = bp[(size_t)(kb + 2) * N], b3 = bp[(size_t)(kb + 3) * N];
            float b4 = bp[(size_t)(kb + 4) * N], b5 = bp[(size_t)(kb + 5) * N];
            float b6 = bp[(size_t)(kb + 6) * N], b7 = bp[(size_t)(kb + 7) * N];
            short8 af, bf;
            af[0] = (short)f2b(a0.x); af[1] = (short)f2b(a0.y);
            af[2] = (short)f2b(a0.z); af[3] = (short)f2b(a0.w);
            af[4] = (short)f2b(a1.x); af[5] = (short)f2b(a1.y);
            af[6] = (short)f2b(a1.z); af[7] = (short)f2b(a1.w);
            bf[0] = (short)f2b(b0); bf[1] = (short)f2b(b1);
            bf[2] = (short)f2b(b2); bf[3] = (short)f2b(b3);
            bf[4] = (short)f2b(b4); bf[5] = (short)f2b(b5);
            bf[6] = (short)f2b(b6); bf[7] = (short)f2b(b7);
            accE = __builtin_amdgcn_mfma_f32_16x16x32_bf16(af, bf, accE, 0, 0, 0);
        }
        // ---- k-step kb+32 (odd accumulator) ----
        {
            const int kc2 = kb + 32;
            float4 a0 = *(const float4*)(ap + kc2);
            float4 a1 = *(const float4*)(ap + kc2 + 4);
            float b0 = bp[(size_t)(kc2 + 0) * N], b1 = bp[(size_t)(kc2 + 1) * N];
            float b2 = bp[(size_t)(kc2 + 2) * N], b3 = bp[(size_t)(kc2 + 3) * N];
            float b4 = bp[(size_t)(kc2 + 4) * N], b5 = bp[(size_t)(kc2 + 5) * N];
            float b6 = bp[(size_t)(kc2 + 6) * N], b7 = bp[(size_t)(kc2 + 7) * N];
            short8 af, bf;
            af[0] = (short)f2b(a0.x); af[1] = (short)f2b(a0.y);
            af[2] = (short)f2b(a0.z); af[3] = (short)f2b(a0.w);
            af[4] = (short)f2b(a1.x); af[5] = (short)f2b(a1.y);
            af[6] = (short)f2b(a1.z); af[7] = (short)f2b(a1.w);
            bf[0] = (short)f2b(b0); bf[1] = (short)f2b(b1);
            bf[2] = (short)f2b(b2); bf[3] = (short)f2b(b3);
            bf[4] = (short)f2b(b4); bf[5] = (short)f2b(b5);
            bf[6] = (short)f2b(b6); bf[7] = (short)f2b(b7);
            accO = __builtin_amdgcn_mfma_f32_16x16x32_bf16(af, bf, accO, 0, 0, 0);
        }
    }

    const float bb = bias ? bias[c0 + lm] : 0.f;
    const int rq = (lane >> 4) << 2;
    float v[4];
    #pragma unroll
    for (int i = 0; i < 4; ++i) {
        v[i] = accE[i] + accO[i] + bb;
        if (act) v[i] = fmaxf(v[i], 0.f);
    }

    if (MODE == 2) {
        // u[r] += sum_cols v * uW ; rows rq+0..3 owned by this 16-lane group
        const float uw = uW[c0 + lm];
        #pragma unroll
        for (int i = 0; i < 4; ++i) {
            float p = v[i] * uw;
            #pragma unroll
            for (int off = 8; off; off >>= 1) p += __shfl_down(p, off, 16);
            if (lm == 0) atomicAdd(&u[r0 + rq + i], p);
        }
        return;
    }
    #pragma unroll
    for (int i = 0; i < 4; ++i)
        out[(size_t)(r0 + rq + i) * N + c0 + lm] = v[i];
    if (MODE == 1) {
        float p = 0.f;
        #pragma unroll
        for (int i = 0; i < 4; ++i)
            p += v[i] * Wd[(r0 + rq + i) * 256 + c0 + lm];
        #pragma unroll
        for (int off = 32; off; off >>= 1) p += __shfl_down(p, off, 64);
        if (lane == 0) atomicAdd(dem, p);
    }
}

__device__ __forceinline__ float sigmoidf(float x) {
    return 1.0f / (1.0f + expf(-x));
}

// final: v = P@u per row -> region scores; block 0 emits dementia pred
__global__ __launch_bounds__(256)
void k_final(const float* __restrict__ P, const float* __restrict__ u,
             const float* __restrict__ dem,
             const float* __restrict__ bc2a, const float* __restrict__ Wc2b,
             const float* __restrict__ bc2b, const float* __restrict__ bd,
             float* __restrict__ out) {
    __shared__ float red[4];
    const int b = blockIdx.x, t = threadIdx.x;
    float pv = P[b * 256 + t] * u[t];
    #pragma unroll
    for (int off = 32; off; off >>= 1) pv += __shfl_down(pv, off, 64);
    if ((t & 63) == 0) red[t >> 6] = pv;
    __syncthreads();
    if (t == 0) {
        float v = red[0] + red[1] + red[2] + red[3];
        float h2 = fmaxf(v + bc2a[0], 0.f);
        out[1 + b] = sigmoidf(h2 * Wc2b[0] + bc2b[0]);
        if (b == 0) out[0] = sigmoidf(*dem + bd[0]);
    }
}

extern "C" void kernel_launch(void* const* d_in, const int* in_sizes, int n_in,
                              void* d_out, int out_size, void* d_ws, size_t ws_size,
                              hipStream_t stream) {
    const float* x    = (const float*)d_in[0];
    const int*   idx  = (const int*)d_in[1];
    const float* Ws1a = (const float*)d_in[3];
    const float* bs1a = (const float*)d_in[4];
    const float* Ws1b = (const float*)d_in[5];
    const float* bs1b = (const float*)d_in[6];
    const float* Ws2a = (const float*)d_in[7];
    const float* bs2a = (const float*)d_in[8];
    const float* Ws2b = (const float*)d_in[9];
    const float* bs2b = (const float*)d_in[10];
    const float* Wc1a = (const float*)d_in[11];
    const float* bc1a = (const float*)d_in[12];
    const float* Wc1b = (const float*)d_in[13];
    const float* bc1b = (const float*)d_in[14];
    const float* Wc2a = (const float*)d_in[15];
    const float* bc2a = (const float*)d_in[16];
    const float* Wc2b = (const float*)d_in[17];
    const float* bc2b = (const float*)d_in[18];
    const float* Wd   = (const float*)d_in[19];
    const float* bd   = (const float*)d_in[20];
    float* out = (float*)d_out;
    const int E = in_sizes[1] / 2;

    float* w    = (float*)d_ws;
    float* P    = w;                  // 65536
    float* Y1   = P + 65536;          // 131072
    float* bufA = Y1 + 131072;        // 131072
    float* bufB = bufA + 131072;      // 131072
    float* feat = bufB + 131072;      // 65536
    float* u    = feat + 65536;       // 256
    float* dem  = u + 256;            // 64 (dem + pad)
    float* Y1p  = dem + 64;

    // split-K slicing for the MFMA GEMM: 938 chunks of BK=32 (T_PAD=30016)
    const long long fixed = (long long)(Y1p - w);
    const long long avail = (long long)(ws_size / 4) - fixed;
    int maxsplit = (avail > 0) ? (int)(avail / 131072) : 0;
    int nz = 0, kc = 0;
    const int CH32 = 938;
    if (maxsplit >= 2) {
        int splits = maxsplit < 56 ? maxsplit : 56;  // 448 blocks; gemm time is
        int cps = (CH32 + splits - 1) / splits;      // split-invariant, fewer
        nz = (CH32 + cps - 1) / cps;                 // partials halve k_reduce
        kc = cps * 32;
    }

    // P = I + C; zero dem, u
    k_init_P<<<256, 256, 0, stream>>>(P, dem, u);
    k_count_edges<<<(E + 255) / 256, 256, 0, stream>>>(idx, E, P);

    // Y1 = x @ Ws1a   (P@(x@W) == (P@x)@W)   — bf16 MFMA, split-K, XCD swizzle
    if (nz > 0) {
        k_gemm_mfma<<<8 * nz, 256, 0, stream>>>(x, Ws1a, Y1p, kc);
        k_reduce<<<256, 256, 0, stream>>>((const float2*)Y1p, (float2*)Y1, nz);
    } else {
        k_zero<<<512, 256, 0, stream>>>(Y1, N_NODES * H_DIM);
        k_gemm_big_atomic<<<dim3(4, 2, 63), 256, 0, stream>>>(x, Ws1a, Y1, 480);
    }

    // stage chain (stream order is the barrier); 16x16 tile per wave, MFMA
    k_mstage<256, 512, 0><<<128, 256, 0, stream>>>(P,    Y1,   bs1a, bufA, 1, 0, 0, 0, 0);
    k_mstage<512, 512, 0><<<128, 256, 0, stream>>>(bufA, Ws1b, bs1b, bufB, 1, 0, 0, 0, 0);
    k_mstage<256, 512, 0><<<128, 256, 0, stream>>>(P,    bufB, 0,    bufA, 0, 0, 0, 0, 0);
    k_mstage<512, 256, 0><<< 64, 256, 0, stream>>>(bufA, Ws2a, bs2a, bufB, 1, 0, 0, 0, 0);
    k_mstage<256, 256, 1><<< 64, 256, 0, stream>>>(bufB, Ws2b, bs2b, feat, 0, Wd, dem, 0, 0);
    k_mstage<256, 256, 0><<< 64, 256, 0, stream>>>(P,    feat, 0,    bufA, 0, 0, 0, 0, 0);
    k_mstage<256, 512, 0><<<128, 256, 0, stream>>>(bufA, Wc1a, bc1a, bufB, 1, 0, 0, 0, 0);
    k_mstage<512, 512, 2><<<128, 256, 0, stream>>>(bufB, Wc1b, bc1b, 0,    1, 0, 0, Wc2a, u);
    k_final<<<256, 256, 0, stream>>>(P, u, dem, bc2a, Wc2b, bc2b, bd, out);
}